// Round 5
// baseline (155.041 us; speedup 1.0000x reference)
//
#include <hip/hip_runtime.h>
#include <hip/hip_fp16.h>
#include <stdint.h>

// out[16384,1024] = fp16(x) @ (fp16(sparsify24(fp16(W))) * scale -> fp16) + bias
#define M_TOT 16384
#define N_TOT 1024
#define K_TOT 1024

typedef _Float16 f16x8 __attribute__((ext_vector_type(8)));
typedef float f32x4 __attribute__((ext_vector_type(4)));
typedef unsigned short ushort4v __attribute__((ext_vector_type(4)));

// async global->LDS DMA, 16B per lane. LDS dest must be wave-uniform base + lane*16.
__device__ inline void gl2lds16(const void* g, void* l) {
    __builtin_amdgcn_global_load_lds(
        (const __attribute__((address_space(1))) void*)(uintptr_t)(g),
        (__attribute__((address_space(3))) void*)(uint32_t)(uintptr_t)(l),
        16, 0, 0);
}

// --- Kernel 1 (fused, verified r0/r1/r3): blocks [0,256) weight prep; rest cast x->fp16.
__global__ void __launch_bounds__(256) prep_and_cast(const float* __restrict__ X,
                                                     const float* __restrict__ W,
                                                     const float* __restrict__ scale_p,
                                                     _Float16* __restrict__ Xh,
                                                     _Float16* __restrict__ wT) {
    const int tid = threadIdx.x;
    if (blockIdx.x < 256) {
        // W[K][N] fp32 -> fp16 -> 2:4 sparsify along N (groups of 4) * scale -> wT[N][K]
        __shared__ _Float16 sT[64 * 68 + 4];   // sT[n][k], stride 68 (pad)
        const float scale = scale_p[0];
        const int k0 = (blockIdx.x & 15) * 64;
        const int n0 = (blockIdx.x >> 4) * 64;
        const int r = tid >> 4;            // 0..15
        const int c4 = (tid & 15) * 4;     // one 2:4 group = one float4
#pragma unroll
        for (int p = 0; p < 4; ++p) {
            const int k = p * 16 + r;
            float4 w4 = *(const float4*)&W[(size_t)(k0 + k) * N_TOT + n0 + c4];
            _Float16 h0 = (_Float16)w4.x, h1 = (_Float16)w4.y, h2 = (_Float16)w4.z, h3 = (_Float16)w4.w;
            float a0 = fabsf((float)h0), a1 = fabsf((float)h1), a2 = fabsf((float)h2), a3 = fabsf((float)h3);
            float lo01 = fminf(a0, a1), hi01 = fmaxf(a0, a1);
            float lo23 = fminf(a2, a3), hi23 = fmaxf(a2, a3);
            float s2 = fmaxf(fminf(hi01, hi23), fmaxf(lo01, lo23));
            sT[(c4 + 0) * 68 + k] = (_Float16)(((a0 >= s2) ? (float)h0 : 0.0f) * scale);
            sT[(c4 + 1) * 68 + k] = (_Float16)(((a1 >= s2) ? (float)h1 : 0.0f) * scale);
            sT[(c4 + 2) * 68 + k] = (_Float16)(((a2 >= s2) ? (float)h2 : 0.0f) * scale);
            sT[(c4 + 3) * 68 + k] = (_Float16)(((a3 >= s2) ? (float)h3 : 0.0f) * scale);
        }
        __syncthreads();
#pragma unroll
        for (int p = 0; p < 4; ++p) {
            const int n = p * 16 + r;
            ushort4v v = *(const ushort4v*)&sT[n * 68 + c4];
            *(ushort4v*)&wT[(size_t)(n0 + n) * K_TOT + k0 + c4] = v;
        }
    } else {
        size_t i = ((size_t)(blockIdx.x - 256) * 256 + tid) * 8;
        float4 x0 = *(const float4*)&X[i];
        float4 x1 = *(const float4*)&X[i + 4];
        f16x8 h;
        h[0] = (_Float16)x0.x; h[1] = (_Float16)x0.y; h[2] = (_Float16)x0.z; h[3] = (_Float16)x0.w;
        h[4] = (_Float16)x1.x; h[5] = (_Float16)x1.y; h[6] = (_Float16)x1.z; h[7] = (_Float16)x1.w;
        *(f16x8*)&Xh[i] = h;
    }
}

// --- Kernel 2: 256x256 tile, 4 waves x (128x128 per wave), BK=32, 3-buffer depth-2
// prefetch, one barrier per phase. LDS-read traffic per CU-phase: 64 KB (was 96) for
// the same 256 MFMAs -- the r0/r1/r3 invariant (time ~ LDS bytes) says this is the
// remaining lever. acc[8][8] = 256 VGPR -> 1 wave/SIMD (512-VGPR budget, lb(256,1)).
// Schedule/swizzle/race-structure identical to verified r3:
//   phase u: {vmcnt(8) [tile u's 8 loads retired]; s_barrier; stage tile u+2 ->
//   buf (u+2)%3 (8 gl2lds); ds_read fb[8]+fa[8]; setprio(1) 64 MFMA setprio(0)}.
__global__ void __launch_bounds__(256, 1) gemm_bt(const _Float16* __restrict__ A,
                                                  const _Float16* __restrict__ Bt,
                                                  const float* __restrict__ bias,
                                                  float* __restrict__ C) {
    __shared__ __align__(16) _Float16 sA[3][256 * 32];   // 48 KiB
    __shared__ __align__(16) _Float16 sB[3][256 * 32];   // 48 KiB

    const int tid = threadIdx.x;
    const int id = blockIdx.x;
    const int by = id & 63;             // M tile 0..63 (by%8 = XCD; A-panel sharers co-XCD)
    const int bx = id >> 6;             // N tile 0..3
    const int wave = tid >> 6;          // 0..3
    const int lane = tid & 63;
    const int wm = wave >> 1;           // 0..1 -> M half (128 rows)
    const int wn = wave & 1;            // 0..1 -> N half (128 cols)
    const int quad = lane >> 4;
    const int l16 = lane & 15;

    // staging: 256 threads cover 64 rows x 64B per gl2lds; 4 per 256x32 tile side.
    // g is invariant under row0 += 64 (64>>1 = 32 ≡ 0 mod 4), so one slot per thread.
    const int row0 = tid >> 2;          // 0..63
    const int s4 = tid & 3;             // 16B slot within row
    const int g = s4 ^ ((row0 >> 1) & 3);   // pre-swizzled global k-group
    const _Float16* gA = A + (size_t)(by * 256 + row0) * K_TOT + g * 8;
    const _Float16* gB = Bt + (size_t)(bx * 256 + row0) * K_TOT + g * 8;
    const int dst0 = row0 * 32 + s4 * 8;    // LDS elem off; byte off == tid*16 (DMA-legal)

    // ds_read side: slot = quad ^ ((row>>1)&3); row ≡ l16 mod 16 -> lane-const XOR
    const int rdoff = l16 * 64 + ((quad ^ ((l16 >> 1) & 3)) << 4);   // bytes

    f32x4 acc[8][8];
#pragma unroll
    for (int i = 0; i < 8; ++i)
#pragma unroll
        for (int j = 0; j < 8; ++j)
            acc[i][j] = (f32x4){0.f, 0.f, 0.f, 0.f};
    f16x8 fa[8], fb[8];

#define STAGE(t, b) do {                                                       \
        const _Float16* sa_ = gA + (size_t)(t) * 32;                           \
        gl2lds16(sa_,                           &sA[b][dst0]);                 \
        gl2lds16(sa_ + (size_t)64 * K_TOT,      &sA[b][dst0 + 64 * 32]);       \
        gl2lds16(sa_ + (size_t)128 * K_TOT,     &sA[b][dst0 + 128 * 32]);      \
        gl2lds16(sa_ + (size_t)192 * K_TOT,     &sA[b][dst0 + 192 * 32]);      \
        const _Float16* sb_ = gB + (size_t)(t) * 32;                           \
        gl2lds16(sb_,                           &sB[b][dst0]);                 \
        gl2lds16(sb_ + (size_t)64 * K_TOT,      &sB[b][dst0 + 64 * 32]);       \
        gl2lds16(sb_ + (size_t)128 * K_TOT,     &sB[b][dst0 + 128 * 32]);      \
        gl2lds16(sb_ + (size_t)192 * K_TOT,     &sB[b][dst0 + 192 * 32]);      \
    } while (0)
#define FENCE asm volatile("" ::: "memory")

    // phase u: read tile from buf b; optionally stage tile t2 -> buf b2
#define PH(b, t2, b2, DO_STAGE, WLAST) do {                                        \
        if (WLAST) asm volatile("s_waitcnt vmcnt(0)" ::: "memory");                \
        else       asm volatile("s_waitcnt vmcnt(8)" ::: "memory");                \
        __builtin_amdgcn_sched_barrier(0);                                         \
        __builtin_amdgcn_s_barrier();                                              \
        FENCE;                                                                     \
        if (DO_STAGE) STAGE(t2, b2);                                               \
        {                                                                          \
            const char* bA_ = (const char*)&sA[b][0] + rdoff + wm * 8192;          \
            const char* bB_ = (const char*)&sB[b][0] + rdoff + wn * 8192;          \
            _Pragma("unroll")                                                      \
            for (int j = 0; j < 8; ++j) fb[j] = *(const f16x8*)(bB_ + j * 1024);   \
            _Pragma("unroll")                                                      \
            for (int i = 0; i < 8; ++i) fa[i] = *(const f16x8*)(bA_ + i * 1024);   \
        }                                                                          \
        __builtin_amdgcn_s_setprio(1);                                             \
        _Pragma("unroll")                                                          \
        for (int i = 0; i < 8; ++i) {                                              \
            _Pragma("unroll")                                                      \
            for (int j = 0; j < 8; ++j)                                            \
                acc[i][j] = __builtin_amdgcn_mfma_f32_16x16x32_f16(                \
                    fa[i], fb[j], acc[i][j], 0, 0, 0);                             \
        }                                                                          \
        __builtin_amdgcn_s_setprio(0);                                             \
    } while (0)

    // prologue: tiles 0 and 1 in flight (16 loads)
    STAGE(0, 0);
    STAGE(1, 1);

    // phases 0..29: read tile u from buf u%3, stage tile u+2 into buf (u+2)%3
    for (int it = 0; it < 10; ++it) {
        const int t = 3 * it;
        PH(0, t + 2, 2, 1, 0);
        PH(1, t + 3, 0, 1, 0);
        PH(2, t + 4, 1, 1, 0);
    }
    PH(0, 0, 0, 0, 0);   // phase 30: tile 30, no stage, vmcnt(8) retires tile 30
    PH(1, 0, 0, 0, 1);   // phase 31: tile 31, no stage, vmcnt(0)

    // epilogue: D row = quad*4 + r (M), col = l16 (N) per 16x16 frag; bias add
#pragma unroll
    for (int j = 0; j < 8; ++j) {
        const int col = bx * 256 + wn * 128 + j * 16 + l16;
        const float bj = bias[col];
#pragma unroll
        for (int mi = 0; mi < 8; ++mi) {
            const int row0o = by * 256 + wm * 128 + mi * 16 + quad * 4;
#pragma unroll
            for (int r = 0; r < 4; ++r) {
                C[(size_t)(row0o + r) * N_TOT + col] = acc[mi][j][r] + bj;
            }
        }
    }

#undef PH
#undef FENCE
#undef STAGE
}

extern "C" void kernel_launch(void* const* d_in, const int* in_sizes, int n_in,
                              void* d_out, int out_size, void* d_ws, size_t ws_size,
                              hipStream_t stream) {
    const float* x      = (const float*)d_in[0];   // [4,4096,1024] fp32
    const float* weight = (const float*)d_in[1];   // [1024,1024] fp32
    const float* bias   = (const float*)d_in[2];   // [1024] fp32
    const float* sscale = (const float*)d_in[3];   // [1] fp32
    float* out = (float*)d_out;

    _Float16* wT = (_Float16*)d_ws;                                    // 2 MiB
    _Float16* xh = (_Float16*)((char*)d_ws + (size_t)2 * 1024 * 1024); // 32 MiB

    prep_and_cast<<<256 + (M_TOT * K_TOT / 8) / 256, 256, 0, stream>>>(x, weight, sscale, xh, wT);
    gemm_bt<<<256, 256, 0, stream>>>(xh, wT, bias, out);
}

// Round 6
// 152.879 us; speedup vs baseline: 1.0141x; 1.0141x over previous
//
#include <hip/hip_runtime.h>
#include <hip/hip_fp16.h>
#include <stdint.h>

// out[16384,1024] = fp16(x) @ (fp16(sparsify24(fp16(W))) * scale -> fp16) + bias
#define M_TOT 16384
#define N_TOT 1024
#define K_TOT 1024

typedef _Float16 f16x8 __attribute__((ext_vector_type(8)));
typedef float f32x4 __attribute__((ext_vector_type(4)));
typedef float f32x16 __attribute__((ext_vector_type(16)));
typedef unsigned short ushort4v __attribute__((ext_vector_type(4)));

// async global->LDS DMA, 16B per lane. LDS dest must be wave-uniform base + lane*16.
__device__ inline void gl2lds16(const void* g, void* l) {
    __builtin_amdgcn_global_load_lds(
        (const __attribute__((address_space(1))) void*)(uintptr_t)(g),
        (__attribute__((address_space(3))) void*)(uint32_t)(uintptr_t)(l),
        16, 0, 0);
}

// --- Kernel 1 (fused, verified r0/r1/r3): blocks [0,256) weight prep; rest cast x->fp16.
__global__ void __launch_bounds__(256) prep_and_cast(const float* __restrict__ X,
                                                     const float* __restrict__ W,
                                                     const float* __restrict__ scale_p,
                                                     _Float16* __restrict__ Xh,
                                                     _Float16* __restrict__ wT) {
    const int tid = threadIdx.x;
    if (blockIdx.x < 256) {
        // W[K][N] fp32 -> fp16 -> 2:4 sparsify along N (groups of 4) * scale -> wT[N][K]
        __shared__ _Float16 sT[64 * 68 + 4];   // sT[n][k], stride 68 (pad)
        const float scale = scale_p[0];
        const int k0 = (blockIdx.x & 15) * 64;
        const int n0 = (blockIdx.x >> 4) * 64;
        const int r = tid >> 4;            // 0..15
        const int c4 = (tid & 15) * 4;     // one 2:4 group = one float4
#pragma unroll
        for (int p = 0; p < 4; ++p) {
            const int k = p * 16 + r;
            float4 w4 = *(const float4*)&W[(size_t)(k0 + k) * N_TOT + n0 + c4];
            _Float16 h0 = (_Float16)w4.x, h1 = (_Float16)w4.y, h2 = (_Float16)w4.z, h3 = (_Float16)w4.w;
            float a0 = fabsf((float)h0), a1 = fabsf((float)h1), a2 = fabsf((float)h2), a3 = fabsf((float)h3);
            float lo01 = fminf(a0, a1), hi01 = fmaxf(a0, a1);
            float lo23 = fminf(a2, a3), hi23 = fmaxf(a2, a3);
            float s2 = fmaxf(fminf(hi01, hi23), fmaxf(lo01, lo23));
            sT[(c4 + 0) * 68 + k] = (_Float16)(((a0 >= s2) ? (float)h0 : 0.0f) * scale);
            sT[(c4 + 1) * 68 + k] = (_Float16)(((a1 >= s2) ? (float)h1 : 0.0f) * scale);
            sT[(c4 + 2) * 68 + k] = (_Float16)(((a2 >= s2) ? (float)h2 : 0.0f) * scale);
            sT[(c4 + 3) * 68 + k] = (_Float16)(((a3 >= s2) ? (float)h3 : 0.0f) * scale);
        }
        __syncthreads();
#pragma unroll
        for (int p = 0; p < 4; ++p) {
            const int n = p * 16 + r;
            ushort4v v = *(const ushort4v*)&sT[n * 68 + c4];
            *(ushort4v*)&wT[(size_t)(n0 + n) * K_TOT + k0 + c4] = v;
        }
    } else {
        size_t i = ((size_t)(blockIdx.x - 256) * 256 + tid) * 8;
        float4 x0 = *(const float4*)&X[i];
        float4 x1 = *(const float4*)&X[i + 4];
        f16x8 h;
        h[0] = (_Float16)x0.x; h[1] = (_Float16)x0.y; h[2] = (_Float16)x0.z; h[3] = (_Float16)x0.w;
        h[4] = (_Float16)x1.x; h[5] = (_Float16)x1.y; h[6] = (_Float16)x1.z; h[7] = (_Float16)x1.w;
        *(f16x8*)&Xh[i] = h;
    }
}

// --- Kernel 2: 256x256 tile, 8 waves (2M x 4N, 128x64 per wave), 32x32x16 MFMA.
// vs r3 (identical 3-buffer depth-2 schedule, 1 barrier/phase, vmcnt(4), same staging
// swizzle): MFMA shape switched 16x16x32 -> 32x32x16 (measured 2382 vs 2075 TF; floor
// 1033 vs 1242 cyc/phase; 16 instead of 32 MFMA instrs/phase/wave), and the epilogue
// uses the 32x32 C layout (col=lane&31) so each store instr covers 2x128B full lines
// (kills the 82MB vs 67MB write amplification of the 64B-segment 16x16 epilogue).
// Per-wave frags: 4(M) x 2(N) of 32x32; per phase K=32 = two chained K=16 slices
// (ascending k order preserved). acc = 8 x f32x16.
__global__ void __launch_bounds__(512, 2) gemm_bt(const _Float16* __restrict__ A,
                                                  const _Float16* __restrict__ Bt,
                                                  const float* __restrict__ bias,
                                                  float* __restrict__ C) {
    __shared__ __align__(16) _Float16 sA[3][256 * 32];   // 48 KiB
    __shared__ __align__(16) _Float16 sB[3][256 * 32];   // 48 KiB

    const int tid = threadIdx.x;
    const int id = blockIdx.x;
    const int by = id & 63;             // M tile 0..63 (by%8 = XCD; A-panel sharers co-XCD)
    const int bx = id >> 6;             // N tile 0..3
    const int wave = tid >> 6;          // 0..7
    const int lane = tid & 63;
    const int wm = wave >> 2;           // 0..1 -> M half (128 rows)
    const int wn = wave & 3;            // 0..3 -> N quarter (64 cols)
    const int l31 = lane & 31;
    const int lhi = lane >> 5;          // k-half within a 32x32x16 frag

    // staging (verbatim r3): 512 threads cover 128 rows x 64B per gl2lds
    const int row0 = tid >> 2;          // 0..127
    const int s4 = tid & 3;             // 16B slot within row
    const int g = s4 ^ ((row0 >> 1) & 3);   // pre-swizzled global k-group
    const _Float16* gA = A + (size_t)(by * 256 + row0) * K_TOT + g * 8;
    const _Float16* gB = Bt + (size_t)(bx * 256 + row0) * K_TOT + g * 8;
    const int dst0 = row0 * 32 + s4 * 8;    // LDS elem off; byte off == tid*16 (DMA-legal)

    // ds_read side for 32x32x16 frags: lane reads row = base32 + l31 (base32 % 32 == 0,
    // so ((row>>1)&3) == ((l31>>1)&3) ^ 0), k-group = 2*ks + lhi; phys slot = g ^ swz.
    const int pb = (l31 >> 1) & 3;
    const int roff = l31 * 64;                 // row byte offset
    const int sl0 = ((0 + lhi) ^ pb) << 4;     // ks=0 slot bytes
    const int sl1 = ((2 + lhi) ^ pb) << 4;     // ks=1 slot bytes

    f32x16 acc[4][2];
#pragma unroll
    for (int m = 0; m < 4; ++m)
#pragma unroll
        for (int n = 0; n < 2; ++n)
#pragma unroll
            for (int r = 0; r < 16; ++r)
                acc[m][n][r] = 0.f;

#define STAGE(t, b) do {                                                   \
        const _Float16* sa_ = gA + (size_t)(t) * 32;                       \
        gl2lds16(sa_, &sA[b][dst0]);                                       \
        gl2lds16(sa_ + (size_t)128 * K_TOT, &sA[b][dst0 + 128 * 32]);      \
        const _Float16* sb_ = gB + (size_t)(t) * 32;                       \
        gl2lds16(sb_, &sB[b][dst0]);                                       \
        gl2lds16(sb_ + (size_t)128 * K_TOT, &sB[b][dst0 + 128 * 32]);      \
    } while (0)
#define FENCE asm volatile("" ::: "memory")

    // phase u: read tile from buf b; optionally stage tile t2 -> buf b2
#define PH(b, t2, b2, DO_STAGE, WLAST) do {                                        \
        if (WLAST) asm volatile("s_waitcnt vmcnt(0)" ::: "memory");                \
        else       asm volatile("s_waitcnt vmcnt(4)" ::: "memory");                \
        __builtin_amdgcn_sched_barrier(0);                                         \
        __builtin_amdgcn_s_barrier();                                              \
        FENCE;                                                                     \
        if (DO_STAGE) STAGE(t2, b2);                                               \
        f16x8 fa0[4], fa1[4], fb0[2], fb1[2];                                      \
        {                                                                          \
            const char* bA_ = (const char*)&sA[b][0] + wm * 8192 + roff;           \
            const char* bB_ = (const char*)&sB[b][0] + wn * 4096 + roff;           \
            _Pragma("unroll")                                                      \
            for (int n = 0; n < 2; ++n) {                                          \
                fb0[n] = *(const f16x8*)(bB_ + n * 2048 + sl0);                    \
                fb1[n] = *(const f16x8*)(bB_ + n * 2048 + sl1);                    \
            }                                                                      \
            _Pragma("unroll")                                                      \
            for (int m = 0; m < 4; ++m) {                                          \
                fa0[m] = *(const f16x8*)(bA_ + m * 2048 + sl0);                    \
                fa1[m] = *(const f16x8*)(bA_ + m * 2048 + sl1);                    \
            }                                                                      \
        }                                                                          \
        __builtin_amdgcn_s_setprio(1);                                             \
        _Pragma("unroll")                                                          \
        for (int m = 0; m < 4; ++m) {                                              \
            _Pragma("unroll")                                                      \
            for (int n = 0; n < 2; ++n)                                            \
                acc[m][n] = __builtin_amdgcn_mfma_f32_32x32x16_f16(                \
                    fa0[m], fb0[n], acc[m][n], 0, 0, 0);                           \
        }                                                                          \
        _Pragma("unroll")                                                          \
        for (int m = 0; m < 4; ++m) {                                              \
            _Pragma("unroll")                                                      \
            for (int n = 0; n < 2; ++n)                                            \
                acc[m][n] = __builtin_amdgcn_mfma_f32_32x32x16_f16(                \
                    fa1[m], fb1[n], acc[m][n], 0, 0, 0);                           \
        }                                                                          \
        __builtin_amdgcn_s_setprio(0);                                             \
    } while (0)

    // prologue: tiles 0 and 1 in flight (8 loads)
    STAGE(0, 0);
    STAGE(1, 1);

    // phases 0..29: read tile u from buf u%3, stage tile u+2 into buf (u+2)%3
    for (int it = 0; it < 10; ++it) {
        const int t = 3 * it;
        PH(0, t + 2, 2, 1, 0);
        PH(1, t + 3, 0, 1, 0);
        PH(2, t + 4, 1, 1, 0);
    }
    PH(0, 0, 0, 0, 0);   // phase 30: tile 30, no stage, vmcnt(4) retires tile 30
    PH(1, 0, 0, 0, 1);   // phase 31: tile 31, no stage, vmcnt(0)

    // epilogue: 32x32 C layout: col = l31, row = (reg&3) + 8*(reg>>2) + 4*lhi.
    // Each store instr: 2 rows x 32 lanes x 4B = 2 x 128B full segments.
#pragma unroll
    for (int n = 0; n < 2; ++n) {
        const int col = bx * 256 + wn * 64 + n * 32 + l31;
        const float bj = bias[col];
#pragma unroll
        for (int m = 0; m < 4; ++m) {
            const int rbase = by * 256 + wm * 128 + m * 32 + 4 * lhi;
#pragma unroll
            for (int reg = 0; reg < 16; ++reg) {
                const int row = rbase + (reg & 3) + 8 * (reg >> 2);
                C[(size_t)row * N_TOT + col] = acc[m][n][reg] + bj;
            }
        }
    }

#undef PH
#undef FENCE
#undef STAGE
}

extern "C" void kernel_launch(void* const* d_in, const int* in_sizes, int n_in,
                              void* d_out, int out_size, void* d_ws, size_t ws_size,
                              hipStream_t stream) {
    const float* x      = (const float*)d_in[0];   // [4,4096,1024] fp32
    const float* weight = (const float*)d_in[1];   // [1024,1024] fp32
    const float* bias   = (const float*)d_in[2];   // [1024] fp32
    const float* sscale = (const float*)d_in[3];   // [1] fp32
    float* out = (float*)d_out;

    _Float16* wT = (_Float16*)d_ws;                                    // 2 MiB
    _Float16* xh = (_Float16*)((char*)d_ws + (size_t)2 * 1024 * 1024); // 32 MiB

    prep_and_cast<<<256 + (M_TOT * K_TOT / 8) / 256, 256, 0, stream>>>(x, weight, sscale, xh, wT);
    gemm_bt<<<256, 512, 0, stream>>>(xh, wT, bias, out);
}